// Round 1
// 1232.496 us; speedup vs baseline: 1.0294x; 1.0294x over previous
//
#include <hip/hip_runtime.h>
#include <math.h>

#define FIN 500
#define NHID 64
#define NCLS 40
#define NLAYERS 8
#define CSHIFT 9                 // 512 rows per coarse bucket
#define CROWS (1 << CSHIFT)
#define PTILE 16384              // edges per partition block

typedef _Float16 half8 __attribute__((ext_vector_type(8)));
typedef float f32x4 __attribute__((ext_vector_type(4)));

// ---------------- prep: transpose weights to fp16 [c][k] ----------------
// WtIn[64][512]  <- W_in[500][64] (zero-padded K to 512)
// WcT[8][64][64] <- conv_W[l][64k][64c]
__global__ __launch_bounds__(256) void k_prep(
    const float* __restrict__ Wi, const float* __restrict__ Wc,
    _Float16* __restrict__ WtIn, _Float16* __restrict__ WcT) {
  const int t = blockIdx.x * 256 + threadIdx.x;
  const int stride = gridDim.x * 256;
  for (int i = t; i < 64 * 512; i += stride) {
    int c = i >> 9, k = i & 511;
    WtIn[i] = (k < FIN) ? (_Float16)Wi[k * 64 + c] : (_Float16)0.f;
  }
  for (int i = t; i < NLAYERS * 64 * 64; i += stride) {
    int l = i >> 12, rem = i & 4095, c = rem >> 6, k = rem & 63;
    WcT[i] = (_Float16)Wc[l * 4096 + k * 64 + c];
  }
}

// ---------------- h0 = relu(x @ W_in + b_in) -> fp16, MFMA ----------------
// block = 256 thr = 4 waves; wave owns 16 rows x 64 cols; K = 512 (padded).
// A-frag: lane row = l&15, k = 8*(l>>4)+j (contiguous 8 -> cvt from f32).
// B-frag: lane col = l&15, k = 8*(l>>4)+j (contiguous from WtIn[c][k]).
// C/D:    lane col = l&15, row = 4*(l>>4)+i.
__global__ __launch_bounds__(256) void k_gemm_in(
    const float* __restrict__ x, const _Float16* __restrict__ Wt,
    const float* __restrict__ b, _Float16* __restrict__ h0, int n) {
  const int lane = threadIdx.x & 63;
  const int wv = threadIdx.x >> 6;
  const int row0 = blockIdx.x * 64 + wv * 16;
  const int arow = row0 + (lane & 15);
  const int gr = (arow < n) ? arow : (n - 1);
  const int kg = (lane >> 4) * 8;
  const float* xrow = x + (size_t)gr * FIN;   // 2000 B rows: 16B-aligned
  f32x4 acc[4];
#pragma unroll
  for (int ct = 0; ct < 4; ++ct) acc[ct] = (f32x4){0.f, 0.f, 0.f, 0.f};
  for (int k0 = 0; k0 < 512; k0 += 32) {
    const int gk = k0 + kg;
    half8 a;
    if (gk + 7 < FIN) {
      float4 u = *reinterpret_cast<const float4*>(xrow + gk);
      float4 v = *reinterpret_cast<const float4*>(xrow + gk + 4);
      a[0] = (_Float16)u.x; a[1] = (_Float16)u.y;
      a[2] = (_Float16)u.z; a[3] = (_Float16)u.w;
      a[4] = (_Float16)v.x; a[5] = (_Float16)v.y;
      a[6] = (_Float16)v.z; a[7] = (_Float16)v.w;
    } else {
#pragma unroll
      for (int j = 0; j < 8; ++j)
        a[j] = (gk + j < FIN) ? (_Float16)xrow[gk + j] : (_Float16)0.f;
    }
#pragma unroll
    for (int ct = 0; ct < 4; ++ct) {
      const half8 bf = *reinterpret_cast<const half8*>(
          Wt + (size_t)(ct * 16 + (lane & 15)) * 512 + gk);
      acc[ct] = __builtin_amdgcn_mfma_f32_16x16x32_f16(a, bf, acc[ct], 0, 0, 0);
    }
  }
  const int orow = row0 + (lane >> 4) * 4;
#pragma unroll
  for (int ct = 0; ct < 4; ++ct) {
    const int c = ct * 16 + (lane & 15);
    const float bb = b[c];
#pragma unroll
    for (int i = 0; i < 4; ++i) {
      const int rr = orow + i;
      if (rr < n)
        h0[(size_t)rr * NHID + c] = (_Float16)fmaxf(acc[ct][i] + bb, 0.f);
    }
  }
}

// ---------------- coarse histogram: 196 buckets, LDS-privatized ----------------
__global__ __launch_bounds__(256) void k_chist(
    const int* __restrict__ row, int* __restrict__ ccnt, int e_total) {
  __shared__ int hist[256];
  const int tid = threadIdx.x;
  hist[tid] = 0;
  __syncthreads();
  const int e0 = blockIdx.x * PTILE;
  for (int t = 0; t < PTILE / 256; ++t) {
    int e = e0 + t * 256 + tid;
    if (e < e_total) atomicAdd(&hist[row[e] >> CSHIFT], 1);
  }
  __syncthreads();
  if (hist[tid]) atomicAdd(&ccnt[tid], hist[tid]);
}

// ---------------- scan 196 coarse counts -> cbase, bcur; ptr[n]=E ----------------
__global__ __launch_bounds__(256) void k_cscan(
    const int* __restrict__ ccnt, int* __restrict__ cbase,
    int* __restrict__ bcur, int* __restrict__ ptr, int nbC, int n, int E) {
  __shared__ int sh[257];
  const int t = threadIdx.x;
  sh[t] = (t < nbC) ? ccnt[t] : 0;
  __syncthreads();
  if (t == 0) {
    int run = 0;
    for (int i = 0; i < 256; ++i) { int v = sh[i]; sh[i] = run; run += v; }
    sh[256] = run;
  }
  __syncthreads();
  if (t <= nbC) cbase[t] = sh[t];
  if (t < nbC) bcur[t] = sh[t];
  if (t == 0) ptr[n] = E;
}

// ---------------- pass 1: block-local coarse partition ----------------
__global__ __launch_bounds__(256) void k_part2(
    const int* __restrict__ row, const int* __restrict__ col,
    const float* __restrict__ w, int* __restrict__ bcurG,
    int2* __restrict__ staged, int e_total, int nbC) {
  __shared__ int hist[256];
  __shared__ int cur[256];
  const int tid = threadIdx.x;
  const int e0 = blockIdx.x * PTILE;
  if (tid < nbC) hist[tid] = 0;
  __syncthreads();
  for (int t = 0; t < PTILE / 256; ++t) {
    int e = e0 + t * 256 + tid;
    if (e < e_total) atomicAdd(&hist[row[e] >> CSHIFT], 1);
  }
  __syncthreads();
  if (tid < nbC) {
    int h = hist[tid];
    cur[tid] = h ? atomicAdd(&bcurG[tid], h) : 0;
  }
  __syncthreads();
  for (int t = 0; t < PTILE / 256; ++t) {
    int e = e0 + t * 256 + tid;
    if (e < e_total) {
      int r = row[e];
      int pos = atomicAdd(&cur[r >> CSHIFT], 1);
      staged[pos] = make_int2(((r & (CROWS - 1)) << 17) | col[e], __float_as_int(w[e]));
    }
  }
}

// ---------------- pass 2: per-bucket row hist + scan -> ptr; place edges ----------------
__global__ __launch_bounds__(256) void k_rebin3(
    const int* __restrict__ cbase, const int2* __restrict__ staged,
    int2* __restrict__ sorted, int* __restrict__ ptr, int n) {
  __shared__ int rcnt[CROWS];
  __shared__ int cur[CROWS];
  __shared__ int wsum[4];
  const int tid = threadIdx.x;
  const int r0 = blockIdx.x << CSHIFT;
  const int bstart = cbase[blockIdx.x], bend = cbase[blockIdx.x + 1];
  rcnt[tid] = 0; rcnt[tid + 256] = 0;
  __syncthreads();
  for (int i = bstart + tid; i < bend; i += 256)
    atomicAdd(&rcnt[staged[i].x >> 17], 1);
  __syncthreads();
  const int lane = tid & 63, wid = tid >> 6;
  int v0 = rcnt[2 * tid], v1 = rcnt[2 * tid + 1];
  int s = v0 + v1;
  int incl = s;
#pragma unroll
  for (int off = 1; off < 64; off <<= 1) {
    int u = __shfl_up(incl, off, 64);
    if (lane >= off) incl += u;
  }
  if (lane == 63) wsum[wid] = incl;
  __syncthreads();
  int woff = 0;
  for (int i = 0; i < wid; ++i) woff += wsum[i];
  int base = bstart + incl - s + woff;
  int rr = r0 + 2 * tid;
  if (rr < n) ptr[rr] = base;
  if (rr + 1 < n) ptr[rr + 1] = base + v0;
  cur[2 * tid] = base;
  cur[2 * tid + 1] = base + v0;
  __syncthreads();
  for (int i = bstart + tid; i < bend; i += 256) {
    int2 e = staged[i];
    int pos = atomicAdd(&cur[e.x >> 17], 1);
    sorted[pos] = make_int2(e.x & 0x1FFFF, e.y);
  }
}

// ---------------- SpMM (CSR, half8 gather) + support blend -> S fp16 ----------------
// one row per wave: 8 edge slots x 8 feature groups; 4-deep unrolled for MLP.
__global__ __launch_bounds__(256) void k_spmm_csr(
    const int* __restrict__ ptr, const int2* __restrict__ sorted,
    const half8* __restrict__ hh, const half8* __restrict__ h0h,
    half8* __restrict__ Sh, int n) {
  const int r = blockIdx.x * 4 + (threadIdx.x >> 6);
  if (r >= n) return;
  const int lane = threadIdx.x & 63;
  const int sub = lane >> 3;       // edge slot 0..7
  const int fl = lane & 7;         // feature group -> feats fl*8..fl*8+7
  const int start = ptr[r], end = ptr[r + 1];
  const half8 h0v = h0h[(size_t)r * 8 + fl];   // hoisted: overlaps with loop
  float acc[8] = {};
  int e = start + sub;
  // 4-deep: 4 edge descriptors then 4 independent gathers in flight
  for (; e + 24 < end; e += 32) {
    const int2 c0 = sorted[e];
    const int2 c1 = sorted[e + 8];
    const int2 c2 = sorted[e + 16];
    const int2 c3 = sorted[e + 24];
    const half8 v0 = hh[(size_t)c0.x * 8 + fl];
    const half8 v1 = hh[(size_t)c1.x * 8 + fl];
    const half8 v2 = hh[(size_t)c2.x * 8 + fl];
    const half8 v3 = hh[(size_t)c3.x * 8 + fl];
    const float w0 = __int_as_float(c0.y);
    const float w1 = __int_as_float(c1.y);
    const float w2 = __int_as_float(c2.y);
    const float w3 = __int_as_float(c3.y);
#pragma unroll
    for (int j = 0; j < 8; ++j)
      acc[j] += w0 * (float)v0[j] + w1 * (float)v1[j] +
                w2 * (float)v2[j] + w3 * (float)v3[j];
  }
  for (; e < end; e += 8) {
    const int2 cw = sorted[e];
    const float wv = __int_as_float(cw.y);
    const half8 hv = hh[(size_t)cw.x * 8 + fl];
#pragma unroll
    for (int j = 0; j < 8; ++j) acc[j] += wv * (float)hv[j];
  }
#pragma unroll
  for (int off = 8; off < 64; off <<= 1)
#pragma unroll
    for (int j = 0; j < 8; ++j) acc[j] += __shfl_xor(acc[j], off, 64);
  if (sub == 0) {
    half8 o;
#pragma unroll
    for (int j = 0; j < 8; ++j)
      o[j] = (_Float16)(0.9f * acc[j] + 0.1f * (float)h0v[j]);
    Sh[(size_t)r * 8 + fl] = o;
  }
}

// ---------------- h = relu(beta*(S@Wl) + (1-beta)*S) -> fp16, MFMA ----------------
// no LDS, no barriers: a-frag/b-frag are contiguous 16B global loads.
__global__ __launch_bounds__(256) void k_layer(
    const _Float16* __restrict__ Sh, const _Float16* __restrict__ Wt,
    _Float16* __restrict__ hout, float beta, int n) {
  const int lane = threadIdx.x & 63;
  const int wv = threadIdx.x >> 6;
  const int row0 = blockIdx.x * 64 + wv * 16;
  const int arow = row0 + (lane & 15);
  const int gr = (arow < n) ? arow : (n - 1);
  const int kg = (lane >> 4) * 8;
  const half8 a0 = *reinterpret_cast<const half8*>(Sh + (size_t)gr * NHID + kg);
  const half8 a1 = *reinterpret_cast<const half8*>(Sh + (size_t)gr * NHID + 32 + kg);
  f32x4 acc[4];
#pragma unroll
  for (int ct = 0; ct < 4; ++ct) acc[ct] = (f32x4){0.f, 0.f, 0.f, 0.f};
#pragma unroll
  for (int ct = 0; ct < 4; ++ct) {
    const int c = ct * 16 + (lane & 15);
    const half8 b0 = *reinterpret_cast<const half8*>(Wt + c * NHID + kg);
    const half8 b1 = *reinterpret_cast<const half8*>(Wt + c * NHID + 32 + kg);
    acc[ct] = __builtin_amdgcn_mfma_f32_16x16x32_f16(a0, b0, acc[ct], 0, 0, 0);
    acc[ct] = __builtin_amdgcn_mfma_f32_16x16x32_f16(a1, b1, acc[ct], 0, 0, 0);
  }
  const float g = 1.f - beta;
  const int orow = row0 + (lane >> 4) * 4;
#pragma unroll
  for (int ct = 0; ct < 4; ++ct) {
    const int c = ct * 16 + (lane & 15);
#pragma unroll
    for (int i = 0; i < 4; ++i) {
      const int rr = orow + i;
      if (rr < n) {
        const float s = (float)Sh[(size_t)rr * NHID + c];   // L1-hot (same rows)
        hout[(size_t)rr * NHID + c] =
            (_Float16)fmaxf(beta * acc[ct][i] + g * s, 0.f);
      }
    }
  }
}

// ---------------- out = log_softmax(h @ W_out + b_out), h in fp16 ----------------
__global__ __launch_bounds__(256) void k_out(
    const _Float16* __restrict__ h, const float* __restrict__ Wo,
    const float* __restrict__ bo, float* __restrict__ out, int n) {
  const int lane = threadIdx.x & 63;
  const int r = blockIdx.x * 4 + (threadIdx.x >> 6);
  if (r >= n) return;
  const float hv = (float)h[(size_t)r * NHID + lane];
  const int j = (lane < NCLS) ? lane : (NCLS - 1);
  float acc = bo[j];
#pragma unroll 16
  for (int k = 0; k < NHID; ++k) {
    float hk = __shfl(hv, k, 64);
    acc += hk * Wo[k * NCLS + j];
  }
  float v = (lane < NCLS) ? acc : -INFINITY;
  float m = v;
#pragma unroll
  for (int off = 32; off; off >>= 1) m = fmaxf(m, __shfl_xor(m, off, 64));
  float e = (lane < NCLS) ? expf(acc - m) : 0.f;
  float s = e;
#pragma unroll
  for (int off = 32; off; off >>= 1) s += __shfl_xor(s, off, 64);
  if (lane < NCLS) out[(size_t)r * NCLS + lane] = acc - m - logf(s);
}

extern "C" void kernel_launch(void* const* d_in, const int* in_sizes, int n_in,
                              void* d_out, int out_size, void* d_ws, size_t ws_size,
                              hipStream_t stream) {
  const float* x  = (const float*)d_in[0];
  const int* row  = (const int*)d_in[1];
  const int* col  = (const int*)d_in[2];
  const float* ew = (const float*)d_in[3];
  const float* Wi = (const float*)d_in[4];
  const float* bi = (const float*)d_in[5];
  const float* Wc = (const float*)d_in[6];
  const float* Wo = (const float*)d_in[7];
  const float* bo = (const float*)d_in[8];
  float* out = (float*)d_out;

  const int n = in_sizes[0] / FIN;   // 100000
  const int E = in_sizes[1];         // 3200000

  // workspace layout (~103 MB)
  half8* h0h   = (half8*)d_ws;                          // n*64 f16
  half8* hhA   = h0h + (size_t)n * 8;                   // n*64 f16
  half8* hhB   = hhA + (size_t)n * 8;                   // n*64 f16
  half8* Sh    = hhB + (size_t)n * 8;                   // n*64 f16 (S buffer)
  float* A     = (float*)(Sh + (size_t)n * 8);          // scratch region (25.6 MB)
  int2*  staged= (int2*)A;                              // E int2 (consumed by rebin3)
  _Float16* WtIn = (_Float16*)A;                        // 64*512 f16 (after staged dead)
  _Float16* WcT  = WtIn + 64 * 512;                     // 8*64*64 f16
  int2*  sorted= (int2*)(A + (size_t)n * NHID);         // E int2
  int*   ptr   = (int*)(sorted + E);                    // n+1
  int*   ccnt  = ptr + (n + 1);                         // 256
  int*   cbase = ccnt + 256;                            // 257
  int*   bcur  = cbase + 257;                           // 256

  const int nbC = (n + CROWS - 1) >> CSHIFT;            // 196
  const int nPB = (E + PTILE - 1) / PTILE;              // 196
  dim3 blk(256);

  // ---- CSR build (hierarchical; amortized over 8 SpMM layers) ----
  hipMemsetAsync(ccnt, 0, 256 * sizeof(int), stream);
  k_chist<<<dim3(nPB), blk, 0, stream>>>(row, ccnt, E);
  k_cscan<<<dim3(1), blk, 0, stream>>>(ccnt, cbase, bcur, ptr, nbC, n, E);
  k_part2<<<dim3(nPB), blk, 0, stream>>>(row, col, ew, bcur, staged, E, nbC);
  k_rebin3<<<dim3(nbC), blk, 0, stream>>>(cbase, staged, sorted, ptr, n);

  // ---- fp16 weight transposes (writes into dead staged region) ----
  k_prep<<<dim3(64), blk, 0, stream>>>(Wi, Wc, WtIn, WcT);

  // ---- dense input projection (MFMA) ----
  k_gemm_in<<<dim3((n + 63) / 64), blk, 0, stream>>>(x, WtIn, bi, (_Float16*)h0h, n);

  // ---- 8 GCNII layers ----
  const half8* hin = h0h;
  for (int l = 0; l < NLAYERS; ++l) {
    half8* hout = (l & 1) ? hhB : hhA;
    k_spmm_csr<<<dim3((n + 3) / 4), blk, 0, stream>>>(ptr, sorted, hin, h0h, Sh, n);
    float beta = logf(0.5f / (float)(l + 1) + 1.f);
    k_layer<<<dim3((n + 63) / 64), blk, 0, stream>>>(
        (const _Float16*)Sh, WcT + (size_t)l * NHID * NHID, (_Float16*)hout, beta, n);
    hin = hout;
  }
  k_out<<<dim3((n + 3) / 4), blk, 0, stream>>>((const _Float16*)hin, Wo, bo, out, n);
}